// Round 3
// baseline (333.113 us; speedup 1.0000x reference)
//
#include <hip/hip_runtime.h>

// PointSample: bilinear grid_sample, align_corners=False, border clamp.
// features: [B=8, H=256, W=256, C=128] fp32 channels-last
// grid:     [B=8, P=8192, 2] fp32 (x, y) in [0, 1]
// out:      [B, P, C] fp32
//
// V3 (resubmit — round 2 bench died on container acquisition, no data):
// 4 points per thread -> 16 independent corner gathers issued before any
// s_waitcnt (diagnostic for latency- vs floor-bound; V1->V2 ILP doubling gave
// exactly 0 delta, and the kernel is absent from rocprof top-5, suggesting the
// measured 330 us is ~2x 161us 1-GiB harness poison fills + ~8us kernel).
// Mapping unchanged: 32 consecutive lanes = one point's 128 channels as
// float4 -> every corner gather is a coalesced 512 B contiguous read.

constexpr int B = 8, H = 256, W = 256, C = 128, P = 8192;
constexpr int C4 = C / 4;           // 32 float4 chunks per point
constexpr int LOG2_C4 = 5;
constexpr int LOG2_P  = 13;         // P = 8192
constexpr int BP      = B * P;      // 65536 points
constexpr int NPT     = 4;          // points per thread
constexpr int QPTS    = BP / NPT;   // 16384

typedef float v4f __attribute__((ext_vector_type(4)));

struct Samp {
    int   i00, i01, i10, i11;       // float4 indices of the 4 corner reads
    float w00, w01, w10, w11;       // bilinear weights
};

__device__ __forceinline__ Samp make_samp(const float2 g, const int pg, const int c4)
{
    const int b = pg >> LOG2_P;
    // mirror reference expression order exactly (verified numerics)
    const float x = g.x * 2.0f - 1.0f;
    const float y = g.y * 2.0f - 1.0f;
    const float ix = ((x + 1.0f) * (float)W - 1.0f) * 0.5f;
    const float iy = ((y + 1.0f) * (float)H - 1.0f) * 0.5f;
    const float x0f = floorf(ix);
    const float y0f = floorf(iy);
    const float wx = ix - x0f;
    const float wy = iy - y0f;
    const int xi = (int)x0f;
    const int yi = (int)y0f;
    const int x0 = min(max(xi,     0), W - 1);
    const int x1 = min(max(xi + 1, 0), W - 1);
    const int y0 = min(max(yi,     0), H - 1);
    const int y1 = min(max(yi + 1, 0), H - 1);

    Samp s;
    const int fb = (b << 21) + c4;          // b * H*W*C4 + c4 (fits in int)
    const int r0 = fb + y0 * (W * C4);
    const int r1 = fb + y1 * (W * C4);
    s.i00 = r0 + x0 * C4;
    s.i01 = r0 + x1 * C4;
    s.i10 = r1 + x0 * C4;
    s.i11 = r1 + x1 * C4;
    s.w00 = (1.0f - wy) * (1.0f - wx);
    s.w01 = (1.0f - wy) * wx;
    s.w10 = wy * (1.0f - wx);
    s.w11 = wy * wx;
    return s;
}

__device__ __forceinline__ v4f blend(const float4 c00, const float4 c01,
                                     const float4 c10, const float4 c11,
                                     const float w00, const float w01,
                                     const float w10, const float w11)
{
    v4f o;
    o.x = c00.x * w00 + c01.x * w01 + c10.x * w10 + c11.x * w11;
    o.y = c00.y * w00 + c01.y * w01 + c10.y * w10 + c11.y * w11;
    o.z = c00.z * w00 + c01.z * w01 + c10.z * w10 + c11.z * w11;
    o.w = c00.w * w00 + c01.w * w01 + c10.w * w10 + c11.w * w11;
    return o;
}

__global__ __launch_bounds__(256) void pointsample_kernel(
    const float4* __restrict__ feat,   // [B*H*W*C4] float4
    const float2* __restrict__ grid,   // [B*P] (x,y)
    v4f*          __restrict__ out)    // [B*P*C4]
{
    const int t  = blockIdx.x * blockDim.x + threadIdx.x;
    const int c4 = t & (C4 - 1);        // channel-quad index 0..31
    const int q  = t >> LOG2_C4;        // 0..QPTS-1

    // grid reads first (L2-resident broadcast across the 32-lane group)
    float2 g[NPT];
#pragma unroll
    for (int k = 0; k < NPT; ++k)
        g[k] = grid[q + k * QPTS];

    Samp s[NPT];
#pragma unroll
    for (int k = 0; k < NPT; ++k)
        s[k] = make_samp(g[k], q + k * QPTS, c4);

    // Issue all 16 independent corner gathers before any use.
    float4 c00[NPT], c01[NPT], c10[NPT], c11[NPT];
#pragma unroll
    for (int k = 0; k < NPT; ++k) {
        c00[k] = feat[s[k].i00];
        c01[k] = feat[s[k].i01];
        c10[k] = feat[s[k].i10];
        c11[k] = feat[s[k].i11];
    }

#pragma unroll
    for (int k = 0; k < NPT; ++k) {
        const v4f o = blend(c00[k], c01[k], c10[k], c11[k],
                            s[k].w00, s[k].w01, s[k].w10, s[k].w11);
        // Non-temporal: output is streamed once, never re-read.
        __builtin_nontemporal_store(o, out + ((q + k * QPTS) << LOG2_C4) + c4);
    }
}

extern "C" void kernel_launch(void* const* d_in, const int* in_sizes, int n_in,
                              void* d_out, int out_size, void* d_ws, size_t ws_size,
                              hipStream_t stream) {
    const float4* feat = (const float4*)d_in[0];
    const float2* grd  = (const float2*)d_in[1];
    v4f*          out  = (v4f*)d_out;

    constexpr int total_threads = BP * C4 / NPT;    // 524,288
    constexpr int block = 256;
    constexpr int nblocks = total_threads / block;  // 2048, exact

    pointsample_kernel<<<nblocks, block, 0, stream>>>(feat, grd, out);
}